// Round 2
// baseline (475.358 us; speedup 1.0000x reference)
//
#include <hip/hip_runtime.h>
#include <math.h>

#define IMGN 32
#define HT 1024
#define WD 1024
#define IMG_STRIDE (HT*WD)
#define NTOT (IMGN*HT*WD)
#define LOSS_THR_F 120.0f

// order-preserving float<->uint maps for atomic min/max
__device__ __forceinline__ unsigned f2ord(float f){
  unsigned u = __float_as_uint(f);
  return (u & 0x80000000u) ? ~u : (u | 0x80000000u);
}
__device__ __forceinline__ float ord2f(unsigned v){
  unsigned u = (v & 0x80000000u) ? (v ^ 0x80000000u) : ~v;
  return __uint_as_float(u);
}

__global__ void k_init(unsigned* ws){
  if (threadIdx.x == 0){ ws[0] = 0xFFFFFFFFu; ws[1] = 0u; }
}

// global min/max over xd. No cross-lane ops, no divergent loads:
// each lane loads its float4 AND the scalar to its left (L1-hit, same line).
__global__ __launch_bounds__(256) void k_minmax(const float* __restrict__ x,
                                                unsigned* __restrict__ ws){
  int t = blockIdx.x*256 + threadIdx.x;     // 8192*256 threads
  const float4* x4 = (const float4*)x;
  float lmin = INFINITY, lmax = -INFINITY;
  #pragma unroll
  for (int k = 0; k < 4; ++k){
    int g = t + k*(8192*256);               // float4 index, 4 iters covers 8M
    float4 v = x4[g];
    float lf = 0.0f;
    if (g & 255) lf = x[(size_t)g*4 - 1];   // row-start (col4==0) -> delta = x
    float d0 = v.x - lf, d1 = v.y - v.x, d2 = v.z - v.y, d3 = v.w - v.z;
    lmin = fminf(lmin, fminf(fminf(d0, d1), fminf(d2, d3)));
    lmax = fmaxf(lmax, fmaxf(fmaxf(d0, d1), fmaxf(d2, d3)));
  }
  #pragma unroll
  for (int off = 32; off; off >>= 1){
    lmin = fminf(lmin, __shfl_xor(lmin, off));
    lmax = fmaxf(lmax, __shfl_xor(lmax, off));
  }
  __shared__ float smin[4], smax[4];
  int wv = threadIdx.x >> 6;
  if ((threadIdx.x & 63) == 0){ smin[wv] = lmin; smax[wv] = lmax; }
  __syncthreads();
  if (threadIdx.x == 0){
    float bmin = fminf(fminf(smin[0], smin[1]), fminf(smin[2], smin[3]));
    float bmax = fmaxf(fmaxf(smax[0], smax[1]), fmaxf(smax[2], smax[3]));
    atomicMin(&ws[0], f2ord(bmin));
    atomicMax(&ws[1], f2ord(bmax));
  }
}

// one 512-thread WG per (8 rows x 32 cols x 32 imgs) tile = 4 sub-blocks.
// Full 128B cachelines per row/img -> no over-fetch.
__global__ __launch_bounds__(512) void k_main(const float* __restrict__ x,
                                              float* __restrict__ out,
                                              const unsigned* __restrict__ ws){
  // dsh[s][p][i]: sub-block stride 2113, pixel stride 33 -> every wave-wide
  // access pattern is <=2-way bank-aliased (free) or broadcast.
  __shared__ float dsh[4*2113];
  __shared__ float xleft[264];              // [r*33 + i]
  __shared__ float s_inv[4][9];
  __shared__ int   s_degen[4];

  const int tid = threadIdx.x;
  // XCD swizzle: full row-strip of 32 tiles -> same XCD, consecutive slots
  const int bid = blockIdx.x;
  const int xcd = bid & 7;
  const int j   = bid >> 3;
  const int hb  = xcd*16 + (j >> 5);        // 0..127
  const int cb  = j & 31;                   // 0..31
  const int row0 = hb << 3;
  const int col0 = cb << 5;

  const float mn = ord2f(ws[0]);
  const float mx = ord2f(ws[1]);
  const bool  neq = (mx != mn);
  const float scale = neq ? (65535.0f / (mx - mn)) : 1.0f;
  const float sinv  = 1.0f / scale;
  const float moff  = neq ? mn : 0.0f;
  // part_quant1: lsb = 2 ** (round(log2(mx / 2^15)) + 1)
  const float lsb = exp2f(rintf(log2f(mx / 32768.0f)) + 1.0f);

  // ---- phase 1: load + delta + quantize/dequant -> dsh (registers only)
  const float4* x4 = (const float4*)x;
  #pragma unroll
  for (int k = 0; k < 4; ++k){
    int f = tid + (k << 9);                 // 0..2047 float4s
    int i = f >> 6;                         // image, const per wave
    int rem = f & 63;
    int r = rem >> 3;
    int fi = rem & 7;                       // float4 within 32-col row
    float4 v = x4[(size_t)i*(IMG_STRIDE/4) + (size_t)(row0+r)*(WD/4) + (col0>>2) + fi];
    int gc0 = col0 + (fi << 2);
    float lf = 0.0f;
    if (gc0 != 0) lf = x[(size_t)i*IMG_STRIDE + (size_t)(row0+r)*WD + gc0 - 1];
    float d0 = v.x - lf, d1 = v.y - v.x, d2 = v.z - v.y, d3 = v.w - v.z;
    float q0, q1, q2, q3;
    if (neq){
      q0 = __fadd_rn(__fmul_rn(rintf((d0 - mn) * scale), sinv), moff);
      q1 = __fadd_rn(__fmul_rn(rintf((d1 - mn) * scale), sinv), moff);
      q2 = __fadd_rn(__fmul_rn(rintf((d2 - mn) * scale), sinv), moff);
      q3 = __fadd_rn(__fmul_rn(rintf((d3 - mn) * scale), sinv), moff);
    } else { q0 = d0; q1 = d1; q2 = d2; q3 = d3; }
    int s = fi >> 1;
    int p = (r << 3) + ((fi & 1) << 2);     // pixel = r*8 + c
    int base = s*2113 + p*33 + i;
    dsh[base]      = q0;
    dsh[base + 33] = q1;
    dsh[base + 66] = q2;
    dsh[base + 99] = q3;
  }
  if (tid < 256){
    int i = tid >> 3, r = tid & 7;
    xleft[r*33 + i] = (cb == 0) ? 0.0f
                    : x[(size_t)i*IMG_STRIDE + (size_t)(row0+r)*WD + col0 - 1];
  }
  __syncthreads();

  // ---- phase 2: normal matrix per sub-block (wave w -> sub-block w)
  if (tid < 256){
    int s = tid >> 6;
    int p = tid & 63;
    float a0 = dsh[s*2113 + p*33 + 0];      // image 0 (A row 0)
    float a1 = dsh[s*2113 + p*33 + 1];      // image 1 (A row 1)
    double s00 = (double)a0*a0, s01 = (double)a0*a1, s02 = a0;
    double s11 = (double)a1*a1, s12 = a1;
    float mx0 = a0, mn0 = a0, mx1 = a1, mn1 = a1;
    #pragma unroll
    for (int off = 32; off; off >>= 1){
      s00 += __shfl_xor(s00, off);
      s01 += __shfl_xor(s01, off);
      s02 += __shfl_xor(s02, off);
      s11 += __shfl_xor(s11, off);
      s12 += __shfl_xor(s12, off);
      mx0 = fmaxf(mx0, __shfl_xor(mx0, off));
      mn0 = fminf(mn0, __shfl_xor(mn0, off));
      mx1 = fmaxf(mx1, __shfl_xor(mx1, off));
      mn1 = fminf(mn1, __shfl_xor(mn1, off));
    }
    if (p == 0){
      double a = (float)s00, b = (float)s01, c = (float)s02;
      double d = (float)s11, e = (float)s12, f = 64.0;
      double c00 = d*f - e*e;
      double c01 = c*e - b*f;
      double c02 = b*e - c*d;
      double det = a*c00 + b*c01 + c*c02;
      float inv[9];
      if (det == 0.0){
        inv[0]=1.f;inv[1]=0.f;inv[2]=0.f;
        inv[3]=0.f;inv[4]=1.f;inv[5]=0.f;
        inv[6]=0.f;inv[7]=0.f;inv[8]=1.f;
      } else {
        double id = 1.0/det;
        double c11 = a*f - c*c;
        double c12 = b*c - a*e;
        double c22 = a*d - b*b;
        inv[0]=(float)(c00*id); inv[1]=(float)(c01*id); inv[2]=(float)(c02*id);
        inv[3]=inv[1];          inv[4]=(float)(c11*id); inv[5]=(float)(c12*id);
        inv[6]=inv[2];          inv[7]=inv[5];          inv[8]=(float)(c22*id);
      }
      #pragma unroll
      for (int jj = 0; jj < 9; ++jj) s_inv[s][jj] = inv[jj];
      s_degen[s] = (((mx0 - mn0) < 1e-6f) && ((mx1 - mn1) < 1e-6f)) ? 1 : 0;
    }
  }
  __syncthreads();

  // ---- phase 3: fit + epilogue; 2 passes cover 4 sub-blocks x 32 imgs x 8 rows
  #pragma unroll
  for (int k = 0; k < 2; ++k){
    const int s     = ((tid >> 8) << 1) + k;   // const per wave
    const int i_img = (tid >> 3) & 31;
    const int sub   = tid & 7;
    const int p0    = sub << 3;
    const int sb    = s*2113;

    float dv[8], a0v[8], a1v[8];
    #pragma unroll
    for (int c2 = 0; c2 < 8; ++c2){
      int off = sb + (p0 + c2)*33;
      dv[c2]  = dsh[off + i_img];
      a0v[c2] = dsh[off + 0];
      a1v[c2] = dsh[off + 1];
    }
    const float i00 = s_inv[s][0], i01 = s_inv[s][1], i02 = s_inv[s][2];
    const float i10 = s_inv[s][3], i11 = s_inv[s][4], i12 = s_inv[s][5];
    const float i20 = s_inv[s][6], i21 = s_inv[s][7], i22 = s_inv[s][8];

    float pc0 = 0.f, pc1 = 0.f, pc2v = 0.f;
    #pragma unroll
    for (int c2 = 0; c2 < 8; ++c2){
      float b0 = __fadd_rn(__fmaf_rn(i01, a1v[c2], __fmul_rn(i00, a0v[c2])), i02);
      float b1 = __fadd_rn(__fmaf_rn(i11, a1v[c2], __fmul_rn(i10, a0v[c2])), i12);
      float b2 = __fadd_rn(__fmaf_rn(i21, a1v[c2], __fmul_rn(i20, a0v[c2])), i22);
      pc0  = __fmaf_rn(b0, dv[c2], pc0);
      pc1  = __fmaf_rn(b1, dv[c2], pc1);
      pc2v = __fmaf_rn(b2, dv[c2], pc2v);
    }
    pc0  += __shfl_xor(pc0, 1);  pc0  += __shfl_xor(pc0, 2);  pc0  += __shfl_xor(pc0, 4);
    pc1  += __shfl_xor(pc1, 1);  pc1  += __shfl_xor(pc1, 2);  pc1  += __shfl_xor(pc1, 4);
    pc2v += __shfl_xor(pc2v, 1); pc2v += __shfl_xor(pc2v, 2); pc2v += __shfl_xor(pc2v, 4);

    const int degen = s_degen[s];
    float r1v[8];
    float loss = 0.f;
    #pragma unroll
    for (int c2 = 0; c2 < 8; ++c2){
      float r  = __fadd_rn(__fmaf_rn(a1v[c2], pc1, __fmul_rn(a0v[c2], pc0)), pc2v);
      float r1 = __fmul_rn(rintf(__fdiv_rn(r, lsb)), lsb);
      r1v[c2] = r1;
      float df = __fsub_rn(dv[c2], r1);
      loss = __fadd_rn(loss, __fmul_rn(df, df));
    }
    loss += __shfl_xor(loss, 1); loss += __shfl_xor(loss, 2); loss += __shfl_xor(loss, 4);
    const bool sel = (!degen) && (loss <= LOSS_THR_F);

    // un-delta: x_left reloaded from global (L2-hot: this WG just fetched it)
    const int gc0 = col0 + (s << 3);
    const size_t rowbase = (size_t)i_img*IMG_STRIDE + (size_t)(row0 + sub)*WD;
    float o[8];
    #pragma unroll
    for (int c2 = 0; c2 < 8; ++c2){
      int gc = gc0 + c2;
      float xl = (gc == 0) ? 0.0f : x[rowbase + gc - 1];
      float rrv = sel ? r1v[c2] : dv[c2];
      o[c2] = rrv + xl;
    }
    *(float4*)(out + rowbase + gc0)     = make_float4(o[0], o[1], o[2], o[3]);
    *(float4*)(out + rowbase + gc0 + 4) = make_float4(o[4], o[5], o[6], o[7]);
  }
}

extern "C" void kernel_launch(void* const* d_in, const int* in_sizes, int n_in,
                              void* d_out, int out_size, void* d_ws, size_t ws_size,
                              hipStream_t stream) {
  const float* x = (const float*)d_in[0];
  float* out = (float*)d_out;
  unsigned* ws = (unsigned*)d_ws;
  hipLaunchKernelGGL(k_init,   dim3(1),    dim3(64),  0, stream, ws);
  hipLaunchKernelGGL(k_minmax, dim3(8192), dim3(256), 0, stream, x, ws);
  hipLaunchKernelGGL(k_main,   dim3(4096), dim3(512), 0, stream, x, out, ws);
}

// Round 3
// 291.337 us; speedup vs baseline: 1.6316x; 1.6316x over previous
//
#include <hip/hip_runtime.h>
#include <math.h>

#define IMGN 32
#define HT 1024
#define WD 1024
#define IMG_STRIDE (HT*WD)
#define LOSS_THR_F 120.0f
#define MMX_BLOCKS 4096

// ---------------- pass 1: global min/max of width-deltas ----------------
// Each wave handles 2 complete 1024-float rows as 8 coalesced float4 loads,
// all issued before any use (deep ILP). Left-neighbors via register shuffles.
// No scalar loads, no divergence, no atomics.
__global__ __launch_bounds__(256) void k_minmax(const float* __restrict__ x,
                                                float* __restrict__ wsf){
  const int lane = threadIdx.x & 63;
  const int wave_id = (blockIdx.x*256 + threadIdx.x) >> 6;   // 0..16383
  const float4* x4 = (const float4*)x;
  const int base4 = wave_id * 512;        // 512 float4 = 2048 floats = 2 rows

  float4 v[8];
  #pragma unroll
  for (int j = 0; j < 8; ++j) v[j] = x4[base4 + j*64 + lane];

  float lmin = INFINITY, lmax = -INFINITY;
  #pragma unroll
  for (int j = 0; j < 8; ++j){
    float lf = __shfl_up(v[j].w, 1);
    // chunks 0 and 4 start a 1024-wide row: delta = x - 0
    float carry = (j == 0 || j == 4) ? 0.0f : __shfl(v[j-1].w, 63);
    if (lane == 0) lf = carry;
    float d0 = v[j].x - lf,      d1 = v[j].y - v[j].x;
    float d2 = v[j].z - v[j].y,  d3 = v[j].w - v[j].z;
    lmin = fminf(lmin, fminf(fminf(d0, d1), fminf(d2, d3)));
    lmax = fmaxf(lmax, fmaxf(fmaxf(d0, d1), fmaxf(d2, d3)));
  }
  #pragma unroll
  for (int off = 32; off; off >>= 1){
    lmin = fminf(lmin, __shfl_xor(lmin, off));
    lmax = fmaxf(lmax, __shfl_xor(lmax, off));
  }
  __shared__ float smin[4], smax[4];
  int wv = threadIdx.x >> 6;
  if (lane == 0){ smin[wv] = lmin; smax[wv] = lmax; }
  __syncthreads();
  if (threadIdx.x == 0){
    wsf[2*blockIdx.x]   = fminf(fminf(smin[0], smin[1]), fminf(smin[2], smin[3]));
    wsf[2*blockIdx.x+1] = fmaxf(fmaxf(smax[0], smax[1]), fmaxf(smax[2], smax[3]));
  }
}

// single-block reduction of the 4096 partials -> wsf[2*MMX_BLOCKS .. +1]
__global__ __launch_bounds__(256) void k_reduce(float* __restrict__ wsf){
  int t = threadIdx.x;
  float mn = INFINITY, mx = -INFINITY;
  #pragma unroll
  for (int j = 0; j < MMX_BLOCKS/256; ++j){
    float2 p = ((const float2*)wsf)[t + 256*j];
    mn = fminf(mn, p.x); mx = fmaxf(mx, p.y);
  }
  #pragma unroll
  for (int off = 32; off; off >>= 1){
    mn = fminf(mn, __shfl_xor(mn, off));
    mx = fmaxf(mx, __shfl_xor(mx, off));
  }
  __shared__ float smin[4], smax[4];
  int wv = t >> 6;
  if ((t & 63) == 0){ smin[wv] = mn; smax[wv] = mx; }
  __syncthreads();
  if (t == 0){
    wsf[2*MMX_BLOCKS]   = fminf(fminf(smin[0], smin[1]), fminf(smin[2], smin[3]));
    wsf[2*MMX_BLOCKS+1] = fmaxf(fmaxf(smax[0], smax[1]), fmaxf(smax[2], smax[3]));
  }
}

// ---------------- pass 2: per-8x8-block fit + output ----------------
// one 512-thread WG per (8 rows x 32 cols x 32 imgs) tile = 4 sub-blocks.
__global__ __launch_bounds__(512) void k_main(const float* __restrict__ x,
                                              float* __restrict__ out,
                                              const float* __restrict__ wsf){
  // dsh[s][p][i]: sub-block stride 2113, pixel stride 33 -> all patterns
  // are <=2-way bank-aliased (free) or broadcast.
  __shared__ float dsh[4*2113];
  __shared__ float s_inv[4][9];
  __shared__ int   s_degen[4];

  const int tid = threadIdx.x;
  const int bid = blockIdx.x;
  const int xcd = bid & 7;
  const int jj  = bid >> 3;
  const int hb  = xcd*16 + (jj >> 5);
  const int cb  = jj & 31;
  const int row0 = hb << 3;
  const int col0 = cb << 5;

  const float mn = wsf[2*MMX_BLOCKS];
  const float mx = wsf[2*MMX_BLOCKS+1];
  const bool  neq = (mx != mn);
  const float scale = neq ? (65535.0f / (mx - mn)) : 1.0f;
  const float sinv  = 1.0f / scale;
  const float moff  = neq ? mn : 0.0f;
  const float lsb = exp2f(rintf(log2f(mx / 32768.0f)) + 1.0f);

  // ---- phase 1: load + delta + quantize/dequant -> dsh
  const float4* x4 = (const float4*)x;
  #pragma unroll
  for (int k = 0; k < 4; ++k){
    int f = tid + (k << 9);                 // 0..2047
    int i = f >> 6;                         // image (const per wave)
    int rem = f & 63;
    int r = rem >> 3;
    int fi = rem & 7;
    float4 v = x4[(size_t)i*(IMG_STRIDE/4) + (size_t)(row0+r)*(WD/4) + (col0>>2) + fi];
    int gc0 = col0 + (fi << 2);
    float lf = 0.0f;
    if (gc0) lf = x[(size_t)i*IMG_STRIDE + (size_t)(row0+r)*WD + gc0 - 1];
    float d0 = v.x - lf, d1 = v.y - v.x, d2 = v.z - v.y, d3 = v.w - v.z;
    float q0, q1, q2, q3;
    if (neq){
      q0 = __fadd_rn(__fmul_rn(rintf((d0 - mn) * scale), sinv), moff);
      q1 = __fadd_rn(__fmul_rn(rintf((d1 - mn) * scale), sinv), moff);
      q2 = __fadd_rn(__fmul_rn(rintf((d2 - mn) * scale), sinv), moff);
      q3 = __fadd_rn(__fmul_rn(rintf((d3 - mn) * scale), sinv), moff);
    } else { q0 = d0; q1 = d1; q2 = d2; q3 = d3; }
    int s = fi >> 1;
    int p = (r << 3) + ((fi & 1) << 2);
    int base = s*2113 + p*33 + i;
    dsh[base]      = q0;
    dsh[base + 33] = q1;
    dsh[base + 66] = q2;
    dsh[base + 99] = q3;
  }
  __syncthreads();

  // ---- phase 2: 3x3 normal matrix per sub-block (wave w -> sub-block w)
  if (tid < 256){
    int s = tid >> 6;
    int p = tid & 63;
    float a0 = dsh[s*2113 + p*33 + 0];
    float a1 = dsh[s*2113 + p*33 + 1];
    double s00 = (double)a0*a0, s01 = (double)a0*a1, s02 = a0;
    double s11 = (double)a1*a1, s12 = a1;
    float mx0 = a0, mn0 = a0, mx1 = a1, mn1 = a1;
    #pragma unroll
    for (int off = 32; off; off >>= 1){
      s00 += __shfl_xor(s00, off);
      s01 += __shfl_xor(s01, off);
      s02 += __shfl_xor(s02, off);
      s11 += __shfl_xor(s11, off);
      s12 += __shfl_xor(s12, off);
      mx0 = fmaxf(mx0, __shfl_xor(mx0, off));
      mn0 = fminf(mn0, __shfl_xor(mn0, off));
      mx1 = fmaxf(mx1, __shfl_xor(mx1, off));
      mn1 = fminf(mn1, __shfl_xor(mn1, off));
    }
    if (p == 0){
      double a = (float)s00, b = (float)s01, c = (float)s02;
      double d = (float)s11, e = (float)s12, f = 64.0;
      double c00 = d*f - e*e;
      double c01 = c*e - b*f;
      double c02 = b*e - c*d;
      double det = a*c00 + b*c01 + c*c02;
      float inv[9];
      if (det == 0.0){
        inv[0]=1.f;inv[1]=0.f;inv[2]=0.f;
        inv[3]=0.f;inv[4]=1.f;inv[5]=0.f;
        inv[6]=0.f;inv[7]=0.f;inv[8]=1.f;
      } else {
        double id = 1.0/det;
        double c11 = a*f - c*c;
        double c12 = b*c - a*e;
        double c22 = a*d - b*b;
        inv[0]=(float)(c00*id); inv[1]=(float)(c01*id); inv[2]=(float)(c02*id);
        inv[3]=inv[1];          inv[4]=(float)(c11*id); inv[5]=(float)(c12*id);
        inv[6]=inv[2];          inv[7]=inv[5];          inv[8]=(float)(c22*id);
      }
      #pragma unroll
      for (int q = 0; q < 9; ++q) s_inv[s][q] = inv[q];
      s_degen[s] = (((mx0 - mn0) < 1e-6f) && ((mx1 - mn1) < 1e-6f)) ? 1 : 0;
    }
  }
  __syncthreads();

  // ---- phase 3: per-image fit. Stage ALL reads, barrier, write rr back.
  const int i_img = (tid >> 3) & 31;
  const int sub   = tid & 7;
  const int p0    = sub << 3;

  float dv[2][8], a0v[2][8], a1v[2][8];
  int ss[2];
  #pragma unroll
  for (int k = 0; k < 2; ++k){
    int s = ((tid >> 8) << 1) + k; ss[k] = s;
    int sb = s*2113;
    #pragma unroll
    for (int c2 = 0; c2 < 8; ++c2){
      int off = sb + (p0 + c2)*33;
      dv[k][c2]  = dsh[off + i_img];
      a0v[k][c2] = dsh[off + 0];
      a1v[k][c2] = dsh[off + 1];
    }
  }
  #pragma unroll
  for (int k = 0; k < 2; ++k){
    const int s = ss[k];
    const float i00 = s_inv[s][0], i01 = s_inv[s][1], i02 = s_inv[s][2];
    const float i10 = s_inv[s][3], i11 = s_inv[s][4], i12 = s_inv[s][5];
    const float i20 = s_inv[s][6], i21 = s_inv[s][7], i22 = s_inv[s][8];

    float pc0 = 0.f, pc1 = 0.f, pc2v = 0.f;
    #pragma unroll
    for (int c2 = 0; c2 < 8; ++c2){
      float b0 = __fadd_rn(__fmaf_rn(i01, a1v[k][c2], __fmul_rn(i00, a0v[k][c2])), i02);
      float b1 = __fadd_rn(__fmaf_rn(i11, a1v[k][c2], __fmul_rn(i10, a0v[k][c2])), i12);
      float b2 = __fadd_rn(__fmaf_rn(i21, a1v[k][c2], __fmul_rn(i20, a0v[k][c2])), i22);
      pc0  = __fmaf_rn(b0, dv[k][c2], pc0);
      pc1  = __fmaf_rn(b1, dv[k][c2], pc1);
      pc2v = __fmaf_rn(b2, dv[k][c2], pc2v);
    }
    pc0  += __shfl_xor(pc0, 1);  pc0  += __shfl_xor(pc0, 2);  pc0  += __shfl_xor(pc0, 4);
    pc1  += __shfl_xor(pc1, 1);  pc1  += __shfl_xor(pc1, 2);  pc1  += __shfl_xor(pc1, 4);
    pc2v += __shfl_xor(pc2v, 1); pc2v += __shfl_xor(pc2v, 2); pc2v += __shfl_xor(pc2v, 4);

    float r1v[8];
    float loss = 0.f;
    #pragma unroll
    for (int c2 = 0; c2 < 8; ++c2){
      float r  = __fadd_rn(__fmaf_rn(a1v[k][c2], pc1, __fmul_rn(a0v[k][c2], pc0)), pc2v);
      float r1 = __fmul_rn(rintf(__fdiv_rn(r, lsb)), lsb);
      r1v[c2] = r1;
      float df = __fsub_rn(dv[k][c2], r1);
      loss = __fadd_rn(loss, __fmul_rn(df, df));
    }
    loss += __shfl_xor(loss, 1); loss += __shfl_xor(loss, 2); loss += __shfl_xor(loss, 4);
    const bool sel = (!s_degen[s]) && (loss <= LOSS_THR_F);
    #pragma unroll
    for (int c2 = 0; c2 < 8; ++c2)
      dv[k][c2] = sel ? r1v[c2] : dv[k][c2];     // rr in registers
  }
  __syncthreads();                                // all reads done everywhere
  #pragma unroll
  for (int k = 0; k < 2; ++k){
    int sb = ss[k]*2113;
    #pragma unroll
    for (int c2 = 0; c2 < 8; ++c2)
      dsh[sb + (p0 + c2)*33 + i_img] = dv[k][c2]; // rr -> LDS
  }
  __syncthreads();

  // ---- phase 4: coalesced epilogue in phase-1 mapping (8 full lines/instr)
  #pragma unroll
  for (int k = 0; k < 4; ++k){
    int f = tid + (k << 9);
    int i = f >> 6;
    int rem = f & 63;
    int r = rem >> 3;
    int fi = rem & 7;
    size_t rowelt = (size_t)i*IMG_STRIDE + (size_t)(row0+r)*WD;
    int gc0 = col0 + (fi << 2);
    float4 v = x4[(rowelt + gc0) >> 2];           // L2-hot re-read
    float lf = 0.0f;
    if (gc0) lf = x[rowelt + gc0 - 1];
    int s = fi >> 1;
    int p = (r << 3) + ((fi & 1) << 2);
    int base = s*2113 + p*33 + i;
    float4 o;
    o.x = dsh[base]      + lf;
    o.y = dsh[base + 33] + v.x;
    o.z = dsh[base + 66] + v.y;
    o.w = dsh[base + 99] + v.z;
    *(float4*)(out + rowelt + gc0) = o;
  }
}

extern "C" void kernel_launch(void* const* d_in, const int* in_sizes, int n_in,
                              void* d_out, int out_size, void* d_ws, size_t ws_size,
                              hipStream_t stream) {
  const float* x = (const float*)d_in[0];
  float* out = (float*)d_out;
  float* wsf = (float*)d_ws;
  hipLaunchKernelGGL(k_minmax, dim3(MMX_BLOCKS), dim3(256), 0, stream, x, wsf);
  hipLaunchKernelGGL(k_reduce, dim3(1),          dim3(256), 0, stream, wsf);
  hipLaunchKernelGGL(k_main,   dim3(4096),       dim3(512), 0, stream, x, out, wsf);
}